// Round 6
// baseline (4275.160 us; speedup 1.0000x reference)
//
#include <hip/hip_runtime.h>
#include <stdint.h>

#define NB 8
#define NPT 16384
#define NM 1024
#define NK 32

// ws layout (float element offsets)
#define WS_W0T 0                    // 67*64 = 4288   W0t[c][o] = W0[o][c]*s0[o]
#define WS_B0  (WS_W0T + 4288)      // 64             b0*s0+t0
#define WS_W1T (WS_B0 + 64)         // 64*128 = 8192
#define WS_B1  (WS_W1T + 8192)      // 128
#define WS_W2T (WS_B1 + 128)        // 128*256 = 32768
#define WS_B2  (WS_W2T + 32768)     // 256
#define WS_IDX (WS_B2 + 256)        // 8192 ints (FPS indices)
#define WS_NXYZ (WS_IDX + 8192)     // 8*1024*3 = 24576 floats
#define WS_BALL (WS_NXYZ + 24576)   // 8*1024*32 = 262144 ints
#define WS_SORT (WS_BALL + 262144)  // float4[8][16384] = 524288 floats (Morton-sorted x,y,z,origidx)
#define WS_END  (WS_SORT + 524288)

// out layout (float element offsets)
#define OUT_XYZ 0
#define OUT_FEAT 24576
#define OUT_IDX (24576 + 2097152)

// ---------------- weight prep: transpose + fold BN scale ----------------
__global__ void prep_weights(const float* __restrict__ W0, const float* __restrict__ b0,
                             const float* __restrict__ s0, const float* __restrict__ t0,
                             const float* __restrict__ W1, const float* __restrict__ b1,
                             const float* __restrict__ s1, const float* __restrict__ t1,
                             const float* __restrict__ W2, const float* __restrict__ b2,
                             const float* __restrict__ s2, const float* __restrict__ t2,
                             float* __restrict__ ws) {
    int id = blockIdx.x * 256 + threadIdx.x;
    if (id < 4288) { int c = id >> 6, o = id & 63;  ws[WS_W0T + id] = W0[o * 67 + c] * s0[o]; return; }
    id -= 4288;
    if (id < 64)   { ws[WS_B0 + id] = fmaf(b0[id], s0[id], t0[id]); return; }
    id -= 64;
    if (id < 8192) { int c = id >> 7, o = id & 127; ws[WS_W1T + id] = W1[o * 64 + c] * s1[o]; return; }
    id -= 8192;
    if (id < 128)  { ws[WS_B1 + id] = fmaf(b1[id], s1[id], t1[id]); return; }
    id -= 128;
    if (id < 32768){ int c = id >> 8, o = id & 255; ws[WS_W2T + id] = W2[o * 128 + c] * s2[o]; return; }
    id -= 32768;
    if (id < 256)  { ws[WS_B2 + id] = fmaf(b2[id], s2[id], t2[id]); return; }
}

#define FOREACH16(M) M(0) M(1) M(2) M(3) M(4) M(5) M(6) M(7) \
                     M(8) M(9) M(10) M(11) M(12) M(13) M(14) M(15)

// ---------------- Morton sort: counting sort by 12-bit Morton cell ----------------
// One block per batch, 1024 threads x 16 points. Output float4{x,y,z,bits(origidx)}.
// Intra-cell order is nondeterministic (LDS atomics) but provably output-invariant:
// dd updates are order-free mins and argmax keys are (value bits, ~orig idx).
__device__ __forceinline__ uint32_t spread3(uint32_t v) {
    return (v & 1u) | ((v & 2u) << 2) | ((v & 4u) << 4) | ((v & 8u) << 6);
}

__global__ __launch_bounds__(1024) void sort_kernel(const float* __restrict__ xyz,
                                                    float4* __restrict__ sorted) {
    int b = blockIdx.x, t = threadIdx.x;
    const float4* __restrict__ Xq = (const float4*)(xyz + (size_t)b * NPT * 3);
    __shared__ uint32_t hist[4096];
    __shared__ uint32_t wtot[16];
    for (int i = t; i < 4096; i += 1024) hist[i] = 0;
    __syncthreads();
    float px[16], py[16], pz[16];
    uint32_t cell[16];
#pragma unroll
    for (int c4 = 0; c4 < 4; c4++) {
        float4 A = Xq[t * 12 + c4 * 3 + 0];
        float4 B = Xq[t * 12 + c4 * 3 + 1];
        float4 C = Xq[t * 12 + c4 * 3 + 2];
        px[c4*4+0]=A.x; py[c4*4+0]=A.y; pz[c4*4+0]=A.z;
        px[c4*4+1]=A.w; py[c4*4+1]=B.x; pz[c4*4+1]=B.y;
        px[c4*4+2]=B.z; py[c4*4+2]=B.w; pz[c4*4+2]=C.x;
        px[c4*4+3]=C.y; py[c4*4+3]=C.z; pz[c4*4+3]=C.w;
    }
#pragma unroll
    for (int u = 0; u < 16; u++) {
        int ix = (int)((px[u] + 4.0f) * 2.0f); ix = ix < 0 ? 0 : (ix > 15 ? 15 : ix);
        int iy = (int)((py[u] + 4.0f) * 2.0f); iy = iy < 0 ? 0 : (iy > 15 ? 15 : iy);
        int iz = (int)((pz[u] + 4.0f) * 2.0f); iz = iz < 0 ? 0 : (iz > 15 ? 15 : iz);
        cell[u] = spread3((uint32_t)ix) | (spread3((uint32_t)iy) << 1) | (spread3((uint32_t)iz) << 2);
        atomicAdd(&hist[cell[u]], 1u);
    }
    __syncthreads();
    // exclusive prefix over 4096 cells: 4 cells/thread + wave scan + wave-total scan
    uint32_t h0 = hist[t*4+0], h1 = hist[t*4+1], h2 = hist[t*4+2], h3 = hist[t*4+3];
    uint32_t s4 = h0 + h1 + h2 + h3;
    int lane = t & 63, w = t >> 6;
    uint32_t sc = s4;
#pragma unroll
    for (int off = 1; off < 64; off <<= 1) { uint32_t v = __shfl_up(sc, off); if (lane >= off) sc += v; }
    if (lane == 63) wtot[w] = sc;
    __syncthreads();
    uint32_t woff = 0;
#pragma unroll
    for (int i = 0; i < 16; i++) if (i < w) woff += wtot[i];
    uint32_t ex = woff + sc - s4;
    hist[t*4+0] = ex; hist[t*4+1] = ex + h0; hist[t*4+2] = ex + h0 + h1; hist[t*4+3] = ex + h0 + h1 + h2;
    __syncthreads();
    float4* __restrict__ out = sorted + (size_t)b * NPT;
#pragma unroll
    for (int u = 0; u < 16; u++) {
        uint32_t pos = atomicAdd(&hist[cell[u]], 1u);
        out[pos] = make_float4(px[u], py[u], pz[u], __uint_as_float((uint32_t)(t * 16 + u)));
    }
}

// ---------------- FPS v2: bounded-group pruning over Morton-sorted points ----------------
// Thread t owns sorted points [16t,16t+16) with bounding sphere (gc, grr) and lazily-
// maintained packed best (dd bits | ~orig). Skip test (conservative, margin 1e-2 abs +
// 1e-4 rel): sqrt(|c-gc|^2) > grr + sqrt(ub) + 0.01  =>  no dd in group can change =>
// stored best stays exact. Update path uses the same _rn ops as the reference (bit-exact).
// Wave max is cached in a register and only recomputed when __any(lane updated).
__global__ __launch_bounds__(1024) void fps2_kernel(const float* __restrict__ xyz,
                                                    const float4* __restrict__ sorted,
                                                    int* __restrict__ out_idx) {
    int b = blockIdx.x, t = threadIdx.x;
    const float* __restrict__ Xp = xyz + (size_t)b * NPT * 3;
    const float4* __restrict__ S = sorted + (size_t)b * NPT + (size_t)t * 16;

#define DECL_DD(j) float dd##j = 1e10f;
    FOREACH16(DECL_DD)
#undef DECL_DD

    float gcx = 0.f, gcy = 0.f, gcz = 0.f;
#pragma unroll
    for (int j = 0; j < 16; j++) { float4 P = S[j]; gcx += P.x; gcy += P.y; gcz += P.z; }
    gcx *= 0.0625f; gcy *= 0.0625f; gcz *= 0.0625f;
    float gr2 = 0.f;
#pragma unroll
    for (int j = 0; j < 16; j++) {
        float4 P = S[j];
        float dx = P.x - gcx, dy = P.y - gcy, dz = P.z - gcz;
        gr2 = fmaxf(gr2, dx*dx + dy*dy + dz*dz);
    }
    float grr = sqrtf(gr2) * 1.0001f + 1e-4f;
    float ubs = 1e5f;                 // sqrt(1e10) upper bound; no skip until first update
    uint64_t best_pk = 0, wave_pk = 0;
    __shared__ uint64_t s_red[2][16];
    int farthest = 0;
    float cx = Xp[0], cy = Xp[1], cz = Xp[2];
    int lane = t & 63, w = t >> 6;
    for (int it = 0; it < NM; ++it) {
        if (t == 0) out_idx[b * NM + it] = farthest;
        float ex = cx - gcx, ey = cy - gcy, ez = cz - gcz;
        float D2 = ex*ex + ey*ey + ez*ez;            // bound math: fma/contract OK
        bool upd = !(sqrtf(D2) > grr + ubs + 0.01f);
        if (__any(upd)) {
            if (upd) {
                uint64_t bp = 0;
#define UPD_PT(j) { float4 P = S[j]; \
        float dx = __fsub_rn(P.x, cx); \
        float dy = __fsub_rn(P.y, cy); \
        float dz = __fsub_rn(P.z, cz); \
        float d  = __fadd_rn(__fadd_rn(__fmul_rn(dx, dx), __fmul_rn(dy, dy)), __fmul_rn(dz, dz)); \
        dd##j = fminf(dd##j, d); \
        uint64_t pk = ((uint64_t)__float_as_uint(dd##j) << 32) | (uint64_t)(uint32_t)(~__float_as_uint(P.w)); \
        if (pk > bp) bp = pk; }
                FOREACH16(UPD_PT)
#undef UPD_PT
                best_pk = bp;
                ubs = sqrtf(__uint_as_float((uint32_t)(bp >> 32)));
            }
            uint64_t m = best_pk;
#pragma unroll
            for (int off = 32; off >= 1; off >>= 1) { uint64_t o = __shfl_xor(m, off); if (o > m) m = o; }
            wave_pk = m;
        }
        if (lane == 0) s_red[it & 1][w] = wave_pk;
        __syncthreads();
        uint64_t m0 = s_red[it & 1][0];
#pragma unroll
        for (int ww = 1; ww < 16; ww++) { uint64_t o = s_red[it & 1][ww]; if (o > m0) m0 = o; }
        int widx = (int)(~(uint32_t)m0);
        farthest = widx;
        const float* cp = Xp + (size_t)widx * 3;   // same addr across wave -> broadcast, L2-hit
        cx = cp[0]; cy = cp[1]; cz = cp[2];
    }
}

// ---------------- FPS fallback (R5 version) if ws too small for sorted copy ----------------
__global__ __attribute__((amdgpu_flat_work_group_size(1024, 1024), amdgpu_waves_per_eu(4, 4)))
void fps_kernel(const float* __restrict__ xyz, int* __restrict__ out_idx) {
    int b = blockIdx.x, t = threadIdx.x;
    const float* __restrict__ Xp = xyz + (size_t)b * NPT * 3;
#define DECL_PT(j) float px##j, py##j, pz##j, dd##j;
    FOREACH16(DECL_PT)
#undef DECL_PT
#define LOAD_PT(j) { int p = t + (j) * 1024; \
        px##j = Xp[p * 3 + 0]; py##j = Xp[p * 3 + 1]; pz##j = Xp[p * 3 + 2]; \
        asm volatile("" : "+v"(px##j), "+v"(py##j), "+v"(pz##j)); \
        dd##j = 1e10f; }
    FOREACH16(LOAD_PT)
#undef LOAD_PT
    __shared__ uint64_t s_red[2][16];
    int farthest = 0;
    float cx = Xp[0], cy = Xp[1], cz = Xp[2];
    for (int it = 0; it < NM; ++it) {
        if (t == 0) out_idx[b * NM + it] = farthest;
        float best = -1.0f; int bi = 0;
#define STEP_PT(j) { \
        float dx = __fsub_rn(px##j, cx); \
        float dy = __fsub_rn(py##j, cy); \
        float dz = __fsub_rn(pz##j, cz); \
        float d  = __fadd_rn(__fadd_rn(__fmul_rn(dx, dx), __fmul_rn(dy, dy)), __fmul_rn(dz, dz)); \
        dd##j = fminf(dd##j, d); \
        if (dd##j > best) { best = dd##j; bi = t + (j) * 1024; } }
        FOREACH16(STEP_PT)
#undef STEP_PT
        uint64_t pk = ((uint64_t)__float_as_uint(best) << 32) | (uint64_t)(uint32_t)(~(uint32_t)bi);
#pragma unroll
        for (int off = 32; off >= 1; off >>= 1) {
            uint64_t o = __shfl_xor(pk, off);
            if (o > pk) pk = o;
        }
        if ((t & 63) == 0) s_red[it & 1][t >> 6] = pk;
        __syncthreads();
        uint64_t m0 = s_red[it & 1][0];
#pragma unroll
        for (int w = 1; w < 16; w++) { uint64_t o = s_red[it & 1][w]; if (o > m0) m0 = o; }
        int widx = (int)(~(uint32_t)m0);
        farthest = widx;
        const float* cp = Xp + (size_t)widx * 3;
        cx = cp[0]; cy = cp[1]; cz = cp[2];
    }
}

// ---------------- gather new_xyz + emit indices as float ----------------
__global__ void gather_newxyz(const float* __restrict__ xyz, const int* __restrict__ idx_ws,
                              float* __restrict__ nxyz_ws, float* __restrict__ out_xyz,
                              float* __restrict__ out_idx_f) {
    int id = blockIdx.x * 256 + threadIdx.x;
    if (id >= NB * NM) return;
    int b = id / NM;
    int p = idx_ws[id];
    const float* Xp = xyz + ((size_t)b * NPT + p) * 3;
    float x = Xp[0], y = Xp[1], z = Xp[2];
    nxyz_ws[id * 3 + 0] = x; nxyz_ws[id * 3 + 1] = y; nxyz_ws[id * 3 + 2] = z;
    out_xyz[id * 3 + 0] = x; out_xyz[id * 3 + 1] = y; out_xyz[id * 3 + 2] = z;
    out_idx_f[id] = (float)p;
}

// ---------------- ball query: first 32 in-radius indices (ascending) ----------------
__global__ __launch_bounds__(256) void ball_query_kernel(const float* __restrict__ xyz,
                                                         const float* __restrict__ nxyz,
                                                         int* __restrict__ ball) {
    int blk = blockIdx.x;
    int b = blk >> 10;
    int t = threadIdx.x;
    const float* Xp = xyz + (size_t)b * NPT * 3;
    float cx = nxyz[blk * 3 + 0], cy = nxyz[blk * 3 + 1], cz = nxyz[blk * 3 + 2];
    const float r2 = (float)(0.4 * 0.4);
    uint64_t mask = 0;
    int base = t * 64;
    const float4* q = (const float4*)(Xp + (size_t)base * 3);
#pragma unroll 4
    for (int c = 0; c < 16; c++) {
        float4 A = q[c * 3 + 0], B = q[c * 3 + 1], C = q[c * 3 + 2];
        float xs[4] = {A.x, A.w, B.z, C.y};
        float ys[4] = {A.y, B.x, B.w, C.z};
        float zs[4] = {A.z, B.y, C.x, C.w};
#pragma unroll
        for (int u = 0; u < 4; u++) {
            float dx = __fsub_rn(xs[u], cx);
            float dy = __fsub_rn(ys[u], cy);
            float dz = __fsub_rn(zs[u], cz);
            float d2 = __fadd_rn(__fadd_rn(__fmul_rn(dx, dx), __fmul_rn(dy, dy)), __fmul_rn(dz, dz));
            if (d2 <= r2) mask |= (1ull << (c * 4 + u));
        }
    }
    int cnt = __popcll(mask);
    int scan = cnt;
    for (int off = 1; off < 64; off <<= 1) {
        int nv = __shfl_up(scan, off);
        if ((t & 63) >= off) scan += nv;
    }
    __shared__ int s_wsum[4];
    __shared__ int s_hit[32];
    int w = t >> 6;
    if ((t & 63) == 63) s_wsum[w] = scan;
    __syncthreads();
    int woff = 0;
    for (int i = 0; i < 4; i++) if (i < w) woff += s_wsum[i];
    int excl = woff + scan - cnt;
    uint64_t mm = mask; int pos = excl;
    while (mm && pos < 32) {
        int j = __ffsll((long long)mm) - 1;
        s_hit[pos] = base + j;
        pos++;
        mm &= mm - 1;
    }
    __syncthreads();
    int total = s_wsum[0] + s_wsum[1] + s_wsum[2] + s_wsum[3];
    if (t < 32) {
        int first = s_hit[0];
        ball[blk * NK + t] = (t < total) ? s_hit[t] : first;
    }
}

// ---------------- fused group + 3xMLP + max over K ----------------
__global__ __attribute__((amdgpu_flat_work_group_size(256, 256), amdgpu_waves_per_eu(2, 2)))
void fused_mlp_kernel(const float* __restrict__ xyz,
                      const float* __restrict__ feats,
                      const float* __restrict__ ws_f,
                      const int* __restrict__ ball,
                      const float* __restrict__ nxyz,
                      float* __restrict__ out_feat) {
    int blk = blockIdx.x;
    int b = blk >> 9;
    int m0 = (blk & 511) * 2;
    int t = threadIdx.x;
    int k = t & 31, g = t >> 5;
    __shared__ float Xs[2][67][32];
    __shared__ float h1[2][64][32];
    __shared__ float h2[2][128][32];
    __shared__ int sidx[2][32];
    const float* W0t = ws_f + WS_W0T; const float* b0f = ws_f + WS_B0;
    const float* W1t = ws_f + WS_W1T; const float* b1f = ws_f + WS_B1;
    const float* W2t = ws_f + WS_W2T; const float* b2f = ws_f + WS_B2;

    if (t < 64) {
        int ctr = t >> 5;
        sidx[ctr][t & 31] = ball[((size_t)b * NM + m0 + ctr) * NK + (t & 31)];
    }
    __syncthreads();

    const float* Xp = xyz + (size_t)b * NPT * 3;
    if (g < 6) {
        int ctr = g / 3, dim = g % 3;
        float cc = nxyz[((size_t)b * NM + m0 + ctr) * 3 + dim];
        Xs[ctr][dim][k] = Xp[sidx[ctr][k] * 3 + dim] - cc;
    }
    const float* Fp = feats + (size_t)b * 64 * NPT;
#pragma unroll
    for (int i = 0; i < 8; i++) {
        int c = g + 8 * i;
        Xs[0][3 + c][k] = Fp[(size_t)c * NPT + sidx[0][k]];
        Xs[1][3 + c][k] = Fp[(size_t)c * NPT + sidx[1][k]];
    }
    __syncthreads();

    {
        float acc0[8], acc1[8];
#pragma unroll
        for (int i = 0; i < 8; i++) { acc0[i] = b0f[g * 8 + i]; acc1[i] = acc0[i]; }
#pragma unroll 4
        for (int c = 0; c < 67; c++) {
            float xv0 = Xs[0][c][k], xv1 = Xs[1][c][k];
            const float* wr = W0t + c * 64 + g * 8;
            float4 wa = *(const float4*)(wr), wb = *(const float4*)(wr + 4);
            acc0[0] = fmaf(wa.x, xv0, acc0[0]); acc1[0] = fmaf(wa.x, xv1, acc1[0]);
            acc0[1] = fmaf(wa.y, xv0, acc0[1]); acc1[1] = fmaf(wa.y, xv1, acc1[1]);
            acc0[2] = fmaf(wa.z, xv0, acc0[2]); acc1[2] = fmaf(wa.z, xv1, acc1[2]);
            acc0[3] = fmaf(wa.w, xv0, acc0[3]); acc1[3] = fmaf(wa.w, xv1, acc1[3]);
            acc0[4] = fmaf(wb.x, xv0, acc0[4]); acc1[4] = fmaf(wb.x, xv1, acc1[4]);
            acc0[5] = fmaf(wb.y, xv0, acc0[5]); acc1[5] = fmaf(wb.y, xv1, acc1[5]);
            acc0[6] = fmaf(wb.z, xv0, acc0[6]); acc1[6] = fmaf(wb.z, xv1, acc1[6]);
            acc0[7] = fmaf(wb.w, xv0, acc0[7]); acc1[7] = fmaf(wb.w, xv1, acc1[7]);
        }
#pragma unroll
        for (int i = 0; i < 8; i++) {
            h1[0][g * 8 + i][k] = fmaxf(acc0[i], 0.0f);
            h1[1][g * 8 + i][k] = fmaxf(acc1[i], 0.0f);
        }
    }
    __syncthreads();

    {
        float acc0[16], acc1[16];
#pragma unroll
        for (int i = 0; i < 16; i++) { acc0[i] = b1f[g * 16 + i]; acc1[i] = acc0[i]; }
#pragma unroll 4
        for (int c = 0; c < 64; c++) {
            float xv0 = h1[0][c][k], xv1 = h1[1][c][k];
            const float4* wr = (const float4*)(W1t + c * 128 + g * 16);
#pragma unroll
            for (int q = 0; q < 4; q++) {
                float4 wv = wr[q];
                acc0[q * 4 + 0] = fmaf(wv.x, xv0, acc0[q * 4 + 0]); acc1[q * 4 + 0] = fmaf(wv.x, xv1, acc1[q * 4 + 0]);
                acc0[q * 4 + 1] = fmaf(wv.y, xv0, acc0[q * 4 + 1]); acc1[q * 4 + 1] = fmaf(wv.y, xv1, acc1[q * 4 + 1]);
                acc0[q * 4 + 2] = fmaf(wv.z, xv0, acc0[q * 4 + 2]); acc1[q * 4 + 2] = fmaf(wv.z, xv1, acc1[q * 4 + 2]);
                acc0[q * 4 + 3] = fmaf(wv.w, xv0, acc0[q * 4 + 3]); acc1[q * 4 + 3] = fmaf(wv.w, xv1, acc1[q * 4 + 3]);
            }
        }
#pragma unroll
        for (int i = 0; i < 16; i++) {
            h2[0][g * 16 + i][k] = fmaxf(acc0[i], 0.0f);
            h2[1][g * 16 + i][k] = fmaxf(acc1[i], 0.0f);
        }
    }
    __syncthreads();

#pragma unroll
    for (int half = 0; half < 2; half++) {
        float acc0[16], acc1[16];
#pragma unroll
        for (int i = 0; i < 16; i++) { acc0[i] = b2f[g * 32 + half * 16 + i]; acc1[i] = acc0[i]; }
#pragma unroll 4
        for (int c = 0; c < 128; c++) {
            float xv0 = h2[0][c][k], xv1 = h2[1][c][k];
            const float4* wr = (const float4*)(W2t + c * 256 + g * 32 + half * 16);
#pragma unroll
            for (int q = 0; q < 4; q++) {
                float4 wv = wr[q];
                acc0[q * 4 + 0] = fmaf(wv.x, xv0, acc0[q * 4 + 0]); acc1[q * 4 + 0] = fmaf(wv.x, xv1, acc1[q * 4 + 0]);
                acc0[q * 4 + 1] = fmaf(wv.y, xv0, acc0[q * 4 + 1]); acc1[q * 4 + 1] = fmaf(wv.y, xv1, acc1[q * 4 + 1]);
                acc0[q * 4 + 2] = fmaf(wv.z, xv0, acc0[q * 4 + 2]); acc1[q * 4 + 2] = fmaf(wv.z, xv1, acc1[q * 4 + 2]);
                acc0[q * 4 + 3] = fmaf(wv.w, xv0, acc0[q * 4 + 3]); acc1[q * 4 + 3] = fmaf(wv.w, xv1, acc1[q * 4 + 3]);
            }
        }
#pragma unroll
        for (int i = 0; i < 16; i++) {
            float v0 = fmaxf(acc0[i], 0.0f);
            float v1 = fmaxf(acc1[i], 0.0f);
#pragma unroll
            for (int off = 16; off >= 1; off >>= 1) {
                v0 = fmaxf(v0, __shfl_xor(v0, off));
                v1 = fmaxf(v1, __shfl_xor(v1, off));
            }
            if (k == 0) {
                size_t o = (size_t)b * 256 + g * 32 + half * 16 + i;
                out_feat[o * NM + m0]     = v0;
                out_feat[o * NM + m0 + 1] = v1;
            }
        }
    }
}

extern "C" void kernel_launch(void* const* d_in, const int* in_sizes, int n_in,
                              void* d_out, int out_size, void* d_ws, size_t ws_size,
                              hipStream_t stream) {
    const float* xyz   = (const float*)d_in[0];
    const float* feats = (const float*)d_in[1];
    const float* W0 = (const float*)d_in[2];  const float* b0 = (const float*)d_in[3];
    const float* s0 = (const float*)d_in[4];  const float* t0 = (const float*)d_in[5];
    const float* W1 = (const float*)d_in[6];  const float* b1 = (const float*)d_in[7];
    const float* s1 = (const float*)d_in[8];  const float* t1 = (const float*)d_in[9];
    const float* W2 = (const float*)d_in[10]; const float* b2 = (const float*)d_in[11];
    const float* s2 = (const float*)d_in[12]; const float* t2 = (const float*)d_in[13];

    float* ws_f = (float*)d_ws;
    int*    idx_ws   = (int*)(ws_f + WS_IDX);
    float*  nxyz_ws  = ws_f + WS_NXYZ;
    int*    ball_ws  = (int*)(ws_f + WS_BALL);
    float4* sorted_ws = (float4*)(ws_f + WS_SORT);

    float* out_f = (float*)d_out;
    float* out_xyz  = out_f + OUT_XYZ;
    float* out_feat = out_f + OUT_FEAT;
    float* out_idxf = out_f + OUT_IDX;

    prep_weights<<<179, 256, 0, stream>>>(W0, b0, s0, t0, W1, b1, s1, t1, W2, b2, s2, t2, ws_f);
    if (ws_size >= (size_t)WS_END * 4) {
        sort_kernel<<<NB, 1024, 0, stream>>>(xyz, sorted_ws);
        fps2_kernel<<<NB, 1024, 0, stream>>>(xyz, sorted_ws, idx_ws);
    } else {
        fps_kernel<<<NB, 1024, 0, stream>>>(xyz, idx_ws);
    }
    gather_newxyz<<<32, 256, 0, stream>>>(xyz, idx_ws, nxyz_ws, out_xyz, out_idxf);
    ball_query_kernel<<<NB * NM, 256, 0, stream>>>(xyz, nxyz_ws, ball_ws);
    fused_mlp_kernel<<<NB * NM / 2, 256, 0, stream>>>(xyz, feats, ws_f, ball_ws, nxyz_ws, out_feat);
}

// Round 7
// 3219.551 us; speedup vs baseline: 1.3279x; 1.3279x over previous
//
#include <hip/hip_runtime.h>
#include <stdint.h>

#define NB 8
#define NPT 16384
#define NM 1024
#define NK 32

// ws layout (float element offsets)
#define WS_W0T 0                    // 67*64 = 4288   W0t[c][o] = W0[o][c]*s0[o]
#define WS_B0  (WS_W0T + 4288)      // 64             b0*s0+t0
#define WS_W1T (WS_B0 + 64)         // 64*128 = 8192
#define WS_B1  (WS_W1T + 8192)      // 128
#define WS_W2T (WS_B1 + 128)        // 128*256 = 32768
#define WS_B2  (WS_W2T + 32768)     // 256
#define WS_IDX (WS_B2 + 256)        // 8192 ints (FPS indices)
#define WS_NXYZ (WS_IDX + 8192)     // 8*1024*3 = 24576 floats
#define WS_BALL (WS_NXYZ + 24576)   // 8*1024*32 = 262144 ints

// out layout (float element offsets)
#define OUT_XYZ 0
#define OUT_FEAT 24576
#define OUT_IDX (24576 + 2097152)

// ---------------- weight prep: transpose + fold BN scale ----------------
__global__ void prep_weights(const float* __restrict__ W0, const float* __restrict__ b0,
                             const float* __restrict__ s0, const float* __restrict__ t0,
                             const float* __restrict__ W1, const float* __restrict__ b1,
                             const float* __restrict__ s1, const float* __restrict__ t1,
                             const float* __restrict__ W2, const float* __restrict__ b2,
                             const float* __restrict__ s2, const float* __restrict__ t2,
                             float* __restrict__ ws) {
    int id = blockIdx.x * 256 + threadIdx.x;
    if (id < 4288) { int c = id >> 6, o = id & 63;  ws[WS_W0T + id] = W0[o * 67 + c] * s0[o]; return; }
    id -= 4288;
    if (id < 64)   { ws[WS_B0 + id] = fmaf(b0[id], s0[id], t0[id]); return; }
    id -= 64;
    if (id < 8192) { int c = id >> 7, o = id & 127; ws[WS_W1T + id] = W1[o * 64 + c] * s1[o]; return; }
    id -= 8192;
    if (id < 128)  { ws[WS_B1 + id] = fmaf(b1[id], s1[id], t1[id]); return; }
    id -= 128;
    if (id < 32768){ int c = id >> 8, o = id & 255; ws[WS_W2T + id] = W2[o * 128 + c] * s2[o]; return; }
    id -= 32768;
    if (id < 256)  { ws[WS_B2 + id] = fmaf(b2[id], s2[id], t2[id]); return; }
}

#define FOREACH16(M) M(0) M(1) M(2) M(3) M(4) M(5) M(6) M(7) \
                     M(8) M(9) M(10) M(11) M(12) M(13) M(14) M(15)

// ---------------- farthest point sampling ----------------
// R6 diagnosis: across R1-R6 the VGPR allocator NEVER kept the 48-float point
// payload in VGPRs (48/88/60/40) -> spill-reload each iteration, ~2x the VALU
// floor. Fix: pin the payload in AGPRs explicitly (gfx950 unified file,
// v_accvgpr_read/write are full-rate VALU). "a"-class values have no register
// competition (only 48 AGPRs live) so they cannot spill; volatile reads keep
// the per-iteration re-read from being hoisted into long-lived VGPRs.
// One barrier/iter via parity-double-buffered s_red; packed u64 argmax
// (dist bits high, ~idx low => unsigned max = first-index-wins argmax).
// Distance math uses _rn intrinsics (no FMA contraction) to bit-match reference.
__global__ __launch_bounds__(1024, 1) void fps_kernel(const float* __restrict__ xyz,
                                                      int* __restrict__ out_idx) {
    int b = blockIdx.x, t = threadIdx.x;
    const float* __restrict__ Xp = xyz + (size_t)b * NPT * 3;

#define DECL_PT(j) float apx##j, apy##j, apz##j, dd##j;
    FOREACH16(DECL_PT)
#undef DECL_PT

#define LOAD_PT(j) { int p = t + (j) * 1024; \
        float x = Xp[p * 3 + 0], y = Xp[p * 3 + 1], z = Xp[p * 3 + 2]; \
        asm volatile("v_accvgpr_write_b32 %0, %1" : "=a"(apx##j) : "v"(x)); \
        asm volatile("v_accvgpr_write_b32 %0, %1" : "=a"(apy##j) : "v"(y)); \
        asm volatile("v_accvgpr_write_b32 %0, %1" : "=a"(apz##j) : "v"(z)); \
        dd##j = 1e10f; }
    FOREACH16(LOAD_PT)
#undef LOAD_PT

    __shared__ uint64_t s_red[2][16];
    int farthest = 0;
    float cx = Xp[0], cy = Xp[1], cz = Xp[2];
    for (int it = 0; it < NM; ++it) {
        if (t == 0) out_idx[b * NM + it] = farthest;
        float best = -1.0f; int bi = 0;
        // ascending j + strict '>' => first-max wins in-thread (idx = t + j*1024 ascends with j)
#define STEP_PT(j) { float x, y, z; \
        asm volatile("v_accvgpr_read_b32 %0, %1" : "=v"(x) : "a"(apx##j)); \
        asm volatile("v_accvgpr_read_b32 %0, %1" : "=v"(y) : "a"(apy##j)); \
        asm volatile("v_accvgpr_read_b32 %0, %1" : "=v"(z) : "a"(apz##j)); \
        float dx = __fsub_rn(x, cx); \
        float dy = __fsub_rn(y, cy); \
        float dz = __fsub_rn(z, cz); \
        float d  = __fadd_rn(__fadd_rn(__fmul_rn(dx, dx), __fmul_rn(dy, dy)), __fmul_rn(dz, dz)); \
        dd##j = fminf(dd##j, d); \
        if (dd##j > best) { best = dd##j; bi = t + (j) * 1024; } }
        FOREACH16(STEP_PT)
#undef STEP_PT
        // pack: high32 = dist bits (positive floats sort as uints), low32 = ~idx (tie -> lower idx)
        uint64_t pk = ((uint64_t)__float_as_uint(best) << 32) | (uint64_t)(uint32_t)(~(uint32_t)bi);
#pragma unroll
        for (int off = 32; off >= 1; off >>= 1) {
            uint64_t o = __shfl_xor(pk, off);
            if (o > pk) pk = o;
        }
        if ((t & 63) == 0) s_red[it & 1][t >> 6] = pk;
        __syncthreads();
        uint64_t m0 = s_red[it & 1][0];
#pragma unroll
        for (int w = 1; w < 16; w++) { uint64_t o = s_red[it & 1][w]; if (o > m0) m0 = o; }
        int widx = (int)(~(uint32_t)m0);
        farthest = widx;
        const float* cp = Xp + (size_t)widx * 3;   // same addr across wave -> broadcast, L2-hit
        cx = cp[0]; cy = cp[1]; cz = cp[2];
    }
}

// ---------------- gather new_xyz + emit indices as float ----------------
__global__ void gather_newxyz(const float* __restrict__ xyz, const int* __restrict__ idx_ws,
                              float* __restrict__ nxyz_ws, float* __restrict__ out_xyz,
                              float* __restrict__ out_idx_f) {
    int id = blockIdx.x * 256 + threadIdx.x;
    if (id >= NB * NM) return;
    int b = id / NM;
    int p = idx_ws[id];
    const float* Xp = xyz + ((size_t)b * NPT + p) * 3;
    float x = Xp[0], y = Xp[1], z = Xp[2];
    nxyz_ws[id * 3 + 0] = x; nxyz_ws[id * 3 + 1] = y; nxyz_ws[id * 3 + 2] = z;
    out_xyz[id * 3 + 0] = x; out_xyz[id * 3 + 1] = y; out_xyz[id * 3 + 2] = z;
    out_idx_f[id] = (float)p;
}

// ---------------- ball query: first 32 in-radius indices (ascending) ----------------
__global__ __launch_bounds__(256) void ball_query_kernel(const float* __restrict__ xyz,
                                                         const float* __restrict__ nxyz,
                                                         int* __restrict__ ball) {
    int blk = blockIdx.x;
    int b = blk >> 10;
    int t = threadIdx.x;
    const float* Xp = xyz + (size_t)b * NPT * 3;
    float cx = nxyz[blk * 3 + 0], cy = nxyz[blk * 3 + 1], cz = nxyz[blk * 3 + 2];
    const float r2 = (float)(0.4 * 0.4);
    uint64_t mask = 0;
    int base = t * 64;
    const float4* q = (const float4*)(Xp + (size_t)base * 3);
#pragma unroll 4
    for (int c = 0; c < 16; c++) {
        float4 A = q[c * 3 + 0], B = q[c * 3 + 1], C = q[c * 3 + 2];
        float xs[4] = {A.x, A.w, B.z, C.y};
        float ys[4] = {A.y, B.x, B.w, C.z};
        float zs[4] = {A.z, B.y, C.x, C.w};
#pragma unroll
        for (int u = 0; u < 4; u++) {
            float dx = __fsub_rn(xs[u], cx);
            float dy = __fsub_rn(ys[u], cy);
            float dz = __fsub_rn(zs[u], cz);
            float d2 = __fadd_rn(__fadd_rn(__fmul_rn(dx, dx), __fmul_rn(dy, dy)), __fmul_rn(dz, dz));
            if (d2 <= r2) mask |= (1ull << (c * 4 + u));
        }
    }
    int cnt = __popcll(mask);
    int scan = cnt;
    for (int off = 1; off < 64; off <<= 1) {
        int nv = __shfl_up(scan, off);
        if ((t & 63) >= off) scan += nv;
    }
    __shared__ int s_wsum[4];
    __shared__ int s_hit[32];
    int w = t >> 6;
    if ((t & 63) == 63) s_wsum[w] = scan;
    __syncthreads();
    int woff = 0;
    for (int i = 0; i < 4; i++) if (i < w) woff += s_wsum[i];
    int excl = woff + scan - cnt;
    uint64_t mm = mask; int pos = excl;
    while (mm && pos < 32) {
        int j = __ffsll((long long)mm) - 1;
        s_hit[pos] = base + j;
        pos++;
        mm &= mm - 1;
    }
    __syncthreads();
    int total = s_wsum[0] + s_wsum[1] + s_wsum[2] + s_wsum[3];
    if (t < 32) {
        int first = s_hit[0];
        ball[blk * NK + t] = (t < total) ? s_hit[t] : first;
    }
}

// ---------------- fused group + 3xMLP + max over K ----------------
__global__ __attribute__((amdgpu_flat_work_group_size(256, 256), amdgpu_waves_per_eu(2, 2)))
void fused_mlp_kernel(const float* __restrict__ xyz,
                      const float* __restrict__ feats,
                      const float* __restrict__ ws_f,
                      const int* __restrict__ ball,
                      const float* __restrict__ nxyz,
                      float* __restrict__ out_feat) {
    int blk = blockIdx.x;
    int b = blk >> 9;
    int m0 = (blk & 511) * 2;
    int t = threadIdx.x;
    int k = t & 31, g = t >> 5;
    __shared__ float Xs[2][67][32];
    __shared__ float h1[2][64][32];
    __shared__ float h2[2][128][32];
    __shared__ int sidx[2][32];
    const float* W0t = ws_f + WS_W0T; const float* b0f = ws_f + WS_B0;
    const float* W1t = ws_f + WS_W1T; const float* b1f = ws_f + WS_B1;
    const float* W2t = ws_f + WS_W2T; const float* b2f = ws_f + WS_B2;

    if (t < 64) {
        int ctr = t >> 5;
        sidx[ctr][t & 31] = ball[((size_t)b * NM + m0 + ctr) * NK + (t & 31)];
    }
    __syncthreads();

    const float* Xp = xyz + (size_t)b * NPT * 3;
    if (g < 6) {
        int ctr = g / 3, dim = g % 3;
        float cc = nxyz[((size_t)b * NM + m0 + ctr) * 3 + dim];
        Xs[ctr][dim][k] = Xp[sidx[ctr][k] * 3 + dim] - cc;
    }
    const float* Fp = feats + (size_t)b * 64 * NPT;
#pragma unroll
    for (int i = 0; i < 8; i++) {
        int c = g + 8 * i;
        Xs[0][3 + c][k] = Fp[(size_t)c * NPT + sidx[0][k]];
        Xs[1][3 + c][k] = Fp[(size_t)c * NPT + sidx[1][k]];
    }
    __syncthreads();

    {
        float acc0[8], acc1[8];
#pragma unroll
        for (int i = 0; i < 8; i++) { acc0[i] = b0f[g * 8 + i]; acc1[i] = acc0[i]; }
#pragma unroll 4
        for (int c = 0; c < 67; c++) {
            float xv0 = Xs[0][c][k], xv1 = Xs[1][c][k];
            const float* wr = W0t + c * 64 + g * 8;
            float4 wa = *(const float4*)(wr), wb = *(const float4*)(wr + 4);
            acc0[0] = fmaf(wa.x, xv0, acc0[0]); acc1[0] = fmaf(wa.x, xv1, acc1[0]);
            acc0[1] = fmaf(wa.y, xv0, acc0[1]); acc1[1] = fmaf(wa.y, xv1, acc1[1]);
            acc0[2] = fmaf(wa.z, xv0, acc0[2]); acc1[2] = fmaf(wa.z, xv1, acc1[2]);
            acc0[3] = fmaf(wa.w, xv0, acc0[3]); acc1[3] = fmaf(wa.w, xv1, acc1[3]);
            acc0[4] = fmaf(wb.x, xv0, acc0[4]); acc1[4] = fmaf(wb.x, xv1, acc1[4]);
            acc0[5] = fmaf(wb.y, xv0, acc0[5]); acc1[5] = fmaf(wb.y, xv1, acc1[5]);
            acc0[6] = fmaf(wb.z, xv0, acc0[6]); acc1[6] = fmaf(wb.z, xv1, acc1[6]);
            acc0[7] = fmaf(wb.w, xv0, acc0[7]); acc1[7] = fmaf(wb.w, xv1, acc1[7]);
        }
#pragma unroll
        for (int i = 0; i < 8; i++) {
            h1[0][g * 8 + i][k] = fmaxf(acc0[i], 0.0f);
            h1[1][g * 8 + i][k] = fmaxf(acc1[i], 0.0f);
        }
    }
    __syncthreads();

    {
        float acc0[16], acc1[16];
#pragma unroll
        for (int i = 0; i < 16; i++) { acc0[i] = b1f[g * 16 + i]; acc1[i] = acc0[i]; }
#pragma unroll 4
        for (int c = 0; c < 64; c++) {
            float xv0 = h1[0][c][k], xv1 = h1[1][c][k];
            const float4* wr = (const float4*)(W1t + c * 128 + g * 16);
#pragma unroll
            for (int q = 0; q < 4; q++) {
                float4 wv = wr[q];
                acc0[q * 4 + 0] = fmaf(wv.x, xv0, acc0[q * 4 + 0]); acc1[q * 4 + 0] = fmaf(wv.x, xv1, acc1[q * 4 + 0]);
                acc0[q * 4 + 1] = fmaf(wv.y, xv0, acc0[q * 4 + 1]); acc1[q * 4 + 1] = fmaf(wv.y, xv1, acc1[q * 4 + 1]);
                acc0[q * 4 + 2] = fmaf(wv.z, xv0, acc0[q * 4 + 2]); acc1[q * 4 + 2] = fmaf(wv.z, xv1, acc1[q * 4 + 2]);
                acc0[q * 4 + 3] = fmaf(wv.w, xv0, acc0[q * 4 + 3]); acc1[q * 4 + 3] = fmaf(wv.w, xv1, acc1[q * 4 + 3]);
            }
        }
#pragma unroll
        for (int i = 0; i < 16; i++) {
            h2[0][g * 16 + i][k] = fmaxf(acc0[i], 0.0f);
            h2[1][g * 16 + i][k] = fmaxf(acc1[i], 0.0f);
        }
    }
    __syncthreads();

#pragma unroll
    for (int half = 0; half < 2; half++) {
        float acc0[16], acc1[16];
#pragma unroll
        for (int i = 0; i < 16; i++) { acc0[i] = b2f[g * 32 + half * 16 + i]; acc1[i] = acc0[i]; }
#pragma unroll 4
        for (int c = 0; c < 128; c++) {
            float xv0 = h2[0][c][k], xv1 = h2[1][c][k];
            const float4* wr = (const float4*)(W2t + c * 256 + g * 32 + half * 16);
#pragma unroll
            for (int q = 0; q < 4; q++) {
                float4 wv = wr[q];
                acc0[q * 4 + 0] = fmaf(wv.x, xv0, acc0[q * 4 + 0]); acc1[q * 4 + 0] = fmaf(wv.x, xv1, acc1[q * 4 + 0]);
                acc0[q * 4 + 1] = fmaf(wv.y, xv0, acc0[q * 4 + 1]); acc1[q * 4 + 1] = fmaf(wv.y, xv1, acc1[q * 4 + 1]);
                acc0[q * 4 + 2] = fmaf(wv.z, xv0, acc0[q * 4 + 2]); acc1[q * 4 + 2] = fmaf(wv.z, xv1, acc1[q * 4 + 2]);
                acc0[q * 4 + 3] = fmaf(wv.w, xv0, acc0[q * 4 + 3]); acc1[q * 4 + 3] = fmaf(wv.w, xv1, acc1[q * 4 + 3]);
            }
        }
#pragma unroll
        for (int i = 0; i < 16; i++) {
            float v0 = fmaxf(acc0[i], 0.0f);
            float v1 = fmaxf(acc1[i], 0.0f);
#pragma unroll
            for (int off = 16; off >= 1; off >>= 1) {
                v0 = fmaxf(v0, __shfl_xor(v0, off));
                v1 = fmaxf(v1, __shfl_xor(v1, off));
            }
            if (k == 0) {
                size_t o = (size_t)b * 256 + g * 32 + half * 16 + i;
                out_feat[o * NM + m0]     = v0;
                out_feat[o * NM + m0 + 1] = v1;
            }
        }
    }
}

extern "C" void kernel_launch(void* const* d_in, const int* in_sizes, int n_in,
                              void* d_out, int out_size, void* d_ws, size_t ws_size,
                              hipStream_t stream) {
    const float* xyz   = (const float*)d_in[0];
    const float* feats = (const float*)d_in[1];
    const float* W0 = (const float*)d_in[2];  const float* b0 = (const float*)d_in[3];
    const float* s0 = (const float*)d_in[4];  const float* t0 = (const float*)d_in[5];
    const float* W1 = (const float*)d_in[6];  const float* b1 = (const float*)d_in[7];
    const float* s1 = (const float*)d_in[8];  const float* t1 = (const float*)d_in[9];
    const float* W2 = (const float*)d_in[10]; const float* b2 = (const float*)d_in[11];
    const float* s2 = (const float*)d_in[12]; const float* t2 = (const float*)d_in[13];

    float* ws_f = (float*)d_ws;
    int*   idx_ws  = (int*)(ws_f + WS_IDX);
    float* nxyz_ws = ws_f + WS_NXYZ;
    int*   ball_ws = (int*)(ws_f + WS_BALL);

    float* out_f = (float*)d_out;
    float* out_xyz  = out_f + OUT_XYZ;
    float* out_feat = out_f + OUT_FEAT;
    float* out_idxf = out_f + OUT_IDX;

    prep_weights<<<179, 256, 0, stream>>>(W0, b0, s0, t0, W1, b1, s1, t1, W2, b2, s2, t2, ws_f);
    fps_kernel<<<NB, 1024, 0, stream>>>(xyz, idx_ws);
    gather_newxyz<<<32, 256, 0, stream>>>(xyz, idx_ws, nxyz_ws, out_xyz, out_idxf);
    ball_query_kernel<<<NB * NM, 256, 0, stream>>>(xyz, nxyz_ws, ball_ws);
    fused_mlp_kernel<<<NB * NM / 2, 256, 0, stream>>>(xyz, feats, ws_f, ball_ws, nxyz_ws, out_feat);
}

// Round 8
// 3128.535 us; speedup vs baseline: 1.3665x; 1.0291x over previous
//
#include <hip/hip_runtime.h>
#include <stdint.h>

#define NB 8
#define NPT 16384
#define NM 1024
#define NK 32

// ws layout (float element offsets)
#define WS_W0T 0                    // 67*64 = 4288   W0t[c][o] = W0[o][c]*s0[o]
#define WS_B0  (WS_W0T + 4288)      // 64             b0*s0+t0
#define WS_W1T (WS_B0 + 64)         // 64*128 = 8192
#define WS_B1  (WS_W1T + 8192)      // 128
#define WS_W2T (WS_B1 + 128)        // 128*256 = 32768
#define WS_B2  (WS_W2T + 32768)     // 256
#define WS_IDX (WS_B2 + 256)        // 8192 ints (FPS indices)
#define WS_NXYZ (WS_IDX + 8192)     // 8*1024*3 = 24576 floats
#define WS_BALL (WS_NXYZ + 24576)   // 8*1024*32 = 262144 ints
#define WS_RELAY (WS_BALL + 262144) // 8*16384*3 = 393216 floats (pair-SoA payload)
#define WS_END  (WS_RELAY + 393216)

// out layout (float element offsets)
#define OUT_XYZ 0
#define OUT_FEAT 24576
#define OUT_IDX (24576 + 2097152)

typedef float fx2 __attribute__((ext_vector_type(2)));

// ---------------- weight prep: transpose + fold BN scale ----------------
__global__ void prep_weights(const float* __restrict__ W0, const float* __restrict__ b0,
                             const float* __restrict__ s0, const float* __restrict__ t0,
                             const float* __restrict__ W1, const float* __restrict__ b1,
                             const float* __restrict__ s1, const float* __restrict__ t1,
                             const float* __restrict__ W2, const float* __restrict__ b2,
                             const float* __restrict__ s2, const float* __restrict__ t2,
                             float* __restrict__ ws) {
    int id = blockIdx.x * 256 + threadIdx.x;
    if (id < 4288) { int c = id >> 6, o = id & 63;  ws[WS_W0T + id] = W0[o * 67 + c] * s0[o]; return; }
    id -= 4288;
    if (id < 64)   { ws[WS_B0 + id] = fmaf(b0[id], s0[id], t0[id]); return; }
    id -= 64;
    if (id < 8192) { int c = id >> 7, o = id & 127; ws[WS_W1T + id] = W1[o * 64 + c] * s1[o]; return; }
    id -= 8192;
    if (id < 128)  { ws[WS_B1 + id] = fmaf(b1[id], s1[id], t1[id]); return; }
    id -= 128;
    if (id < 32768){ int c = id >> 8, o = id & 255; ws[WS_W2T + id] = W2[o * 128 + c] * s2[o]; return; }
    id -= 32768;
    if (id < 256)  { ws[WS_B2 + id] = fmaf(b2[id], s2[id], t2[id]); return; }
}

#define FOREACH8(M) M(0) M(1) M(2) M(3) M(4) M(5) M(6) M(7)
#define FOREACH16(M) M(0) M(1) M(2) M(3) M(4) M(5) M(6) M(7) \
                     M(8) M(9) M(10) M(11) M(12) M(13) M(14) M(15)

// ---------------- payload relayout: pair-SoA, 192B contiguous per thread ----------------
// Thread t's 16 points (orig idx t + j*1024) packed as 8 x [x_2k,x_2k+1, y.., z..]
// so fps3 loads are base + immediate offsets (1 addr calc + 24 dwordx2 per iter max).
__global__ __launch_bounds__(1024) void relayout_kernel(const float* __restrict__ xyz,
                                                         float* __restrict__ RL) {
    int b = blockIdx.x, t = threadIdx.x;
    const float* __restrict__ Xp = xyz + (size_t)b * NPT * 3;
    float* __restrict__ o = RL + (size_t)b * NPT * 3 + (size_t)t * 48;
#pragma unroll
    for (int k = 0; k < 8; k++) {
        int j0 = t + (2 * k) * 1024, j1 = t + (2 * k + 1) * 1024;
        o[k * 6 + 0] = Xp[j0 * 3 + 0]; o[k * 6 + 1] = Xp[j1 * 3 + 0];
        o[k * 6 + 2] = Xp[j0 * 3 + 1]; o[k * 6 + 3] = Xp[j1 * 3 + 1];
        o[k * 6 + 4] = Xp[j0 * 3 + 2]; o[k * 6 + 5] = Xp[j1 * 3 + 2];
    }
}

// ---------------- farthest point sampling v3: packed-f32 + lean reduce ----------------
// R7 evidence: pure VALU-issue-bound (VALUBusy = 93% of the 8-CU ceiling). So: cut
// instructions. (1) pair-SoA payload -> imm-offset loads (no per-load addressing);
// (2) v_pk_add/mul_f32 inline asm: 2 IEEE-RN f32 ops/inst, bitwise == scalar; sub
// done as x + (-c) (exact). (3) tail reduce: lane reads s_red[lane&15], 4-level
// 16-lane butterfly instead of 16-entry serial scan in every thread.
// Packed u64 (dist bits | ~idx) argmax = unsigned max, first-index tie-break.
__global__ __attribute__((amdgpu_flat_work_group_size(1024, 1024), amdgpu_waves_per_eu(4, 4)))
void fps3_kernel(const float* __restrict__ xyz, const float* __restrict__ RL,
                 int* __restrict__ out_idx) {
    int b = blockIdx.x, t = threadIdx.x;
    const float* __restrict__ Xp = xyz + (size_t)b * NPT * 3;
    const float* __restrict__ RLt = RL + (size_t)b * NPT * 3 + (size_t)t * 48;

#define DECL_PAIR(k) fx2 px##k, py##k, pz##k; float ddA##k, ddB##k;
    FOREACH8(DECL_PAIR)
#undef DECL_PAIR

#define LOAD_PAIR(k) { \
        px##k = *(const fx2*)(RLt + (k) * 6 + 0); \
        py##k = *(const fx2*)(RLt + (k) * 6 + 2); \
        pz##k = *(const fx2*)(RLt + (k) * 6 + 4); \
        ddA##k = 1e10f; ddB##k = 1e10f; }
    FOREACH8(LOAD_PAIR)
#undef LOAD_PAIR

    __shared__ uint64_t s_red[2][16];
    int farthest = 0;
    float cx = Xp[0], cy = Xp[1], cz = Xp[2];
    int lane = t & 63, w = t >> 6;
    for (int it = 0; it < NM; ++it) {
        if (t == 0) out_idx[b * NM + it] = farthest;
        float mcx = -cx, mcy = -cy, mcz = -cz;
        fx2 ncx; ncx.x = mcx; ncx.y = mcx;
        fx2 ncy; ncy.x = mcy; ncy.y = mcy;
        fx2 ncz; ncz.x = mcz; ncz.y = mcz;
        float best = -1.0f; int bi = 0;
        // p + (-c) is bitwise == p - c (IEEE); pk ops are 2x scalar-identical RN f32 ops.
        // ascending j (pair k: j=2k then 2k+1) + strict '>' => first-max wins in-thread.
#define STEP_PAIR(k) { fx2 dx, dy, dz, sxy, d; \
        asm("v_pk_add_f32 %0, %1, %2" : "=v"(dx) : "v"(px##k), "v"(ncx)); \
        asm("v_pk_add_f32 %0, %1, %2" : "=v"(dy) : "v"(py##k), "v"(ncy)); \
        asm("v_pk_add_f32 %0, %1, %2" : "=v"(dz) : "v"(pz##k), "v"(ncz)); \
        asm("v_pk_mul_f32 %0, %1, %1" : "=v"(dx) : "v"(dx)); \
        asm("v_pk_mul_f32 %0, %1, %1" : "=v"(dy) : "v"(dy)); \
        asm("v_pk_mul_f32 %0, %1, %1" : "=v"(dz) : "v"(dz)); \
        asm("v_pk_add_f32 %0, %1, %2" : "=v"(sxy) : "v"(dx), "v"(dy)); \
        asm("v_pk_add_f32 %0, %1, %2" : "=v"(d) : "v"(sxy), "v"(dz)); \
        ddA##k = fminf(ddA##k, d.x); \
        if (ddA##k > best) { best = ddA##k; bi = t + (2 * (k)) * 1024; } \
        ddB##k = fminf(ddB##k, d.y); \
        if (ddB##k > best) { best = ddB##k; bi = t + (2 * (k) + 1) * 1024; } }
        FOREACH8(STEP_PAIR)
#undef STEP_PAIR
        // pack: high32 = dist bits (positive floats sort as uints), low32 = ~idx (tie -> lower idx)
        uint64_t pk = ((uint64_t)__float_as_uint(best) << 32) | (uint64_t)(uint32_t)(~(uint32_t)bi);
#pragma unroll
        for (int off = 32; off >= 1; off >>= 1) {
            uint64_t o = __shfl_xor(pk, off);
            if (o > pk) pk = o;
        }
        if (lane == 0) s_red[it & 1][w] = pk;
        __syncthreads();
        uint64_t m0 = s_red[it & 1][lane & 15];
#pragma unroll
        for (int off = 1; off < 16; off <<= 1) {
            uint64_t o = __shfl_xor(m0, off);
            if (o > m0) m0 = o;
        }
        int widx = (int)(~(uint32_t)m0);
        farthest = widx;
        const float* cp = Xp + (size_t)widx * 3;   // same addr across wave -> broadcast, L2-hit
        cx = cp[0]; cy = cp[1]; cz = cp[2];
    }
}

// ---------------- FPS fallback (R5 version) if ws too small for relayout ----------------
__global__ __attribute__((amdgpu_flat_work_group_size(1024, 1024), amdgpu_waves_per_eu(4, 4)))
void fps_fallback_kernel(const float* __restrict__ xyz, int* __restrict__ out_idx) {
    int b = blockIdx.x, t = threadIdx.x;
    const float* __restrict__ Xp = xyz + (size_t)b * NPT * 3;
#define DECL_PT(j) float px##j, py##j, pz##j, dd##j;
    FOREACH16(DECL_PT)
#undef DECL_PT
#define LOAD_PT(j) { int p = t + (j) * 1024; \
        px##j = Xp[p * 3 + 0]; py##j = Xp[p * 3 + 1]; pz##j = Xp[p * 3 + 2]; \
        dd##j = 1e10f; }
    FOREACH16(LOAD_PT)
#undef LOAD_PT
    __shared__ uint64_t s_red[2][16];
    int farthest = 0;
    float cx = Xp[0], cy = Xp[1], cz = Xp[2];
    for (int it = 0; it < NM; ++it) {
        if (t == 0) out_idx[b * NM + it] = farthest;
        float best = -1.0f; int bi = 0;
#define STEP_PT(j) { \
        float dx = __fsub_rn(px##j, cx); \
        float dy = __fsub_rn(py##j, cy); \
        float dz = __fsub_rn(pz##j, cz); \
        float d  = __fadd_rn(__fadd_rn(__fmul_rn(dx, dx), __fmul_rn(dy, dy)), __fmul_rn(dz, dz)); \
        dd##j = fminf(dd##j, d); \
        if (dd##j > best) { best = dd##j; bi = t + (j) * 1024; } }
        FOREACH16(STEP_PT)
#undef STEP_PT
        uint64_t pk = ((uint64_t)__float_as_uint(best) << 32) | (uint64_t)(uint32_t)(~(uint32_t)bi);
#pragma unroll
        for (int off = 32; off >= 1; off >>= 1) {
            uint64_t o = __shfl_xor(pk, off);
            if (o > pk) pk = o;
        }
        if ((t & 63) == 0) s_red[it & 1][t >> 6] = pk;
        __syncthreads();
        uint64_t m0 = s_red[it & 1][0];
#pragma unroll
        for (int w = 1; w < 16; w++) { uint64_t o = s_red[it & 1][w]; if (o > m0) m0 = o; }
        int widx = (int)(~(uint32_t)m0);
        farthest = widx;
        const float* cp = Xp + (size_t)widx * 3;
        cx = cp[0]; cy = cp[1]; cz = cp[2];
    }
}

// ---------------- gather new_xyz + emit indices as float ----------------
__global__ void gather_newxyz(const float* __restrict__ xyz, const int* __restrict__ idx_ws,
                              float* __restrict__ nxyz_ws, float* __restrict__ out_xyz,
                              float* __restrict__ out_idx_f) {
    int id = blockIdx.x * 256 + threadIdx.x;
    if (id >= NB * NM) return;
    int b = id / NM;
    int p = idx_ws[id];
    const float* Xp = xyz + ((size_t)b * NPT + p) * 3;
    float x = Xp[0], y = Xp[1], z = Xp[2];
    nxyz_ws[id * 3 + 0] = x; nxyz_ws[id * 3 + 1] = y; nxyz_ws[id * 3 + 2] = z;
    out_xyz[id * 3 + 0] = x; out_xyz[id * 3 + 1] = y; out_xyz[id * 3 + 2] = z;
    out_idx_f[id] = (float)p;
}

// ---------------- ball query: first 32 in-radius indices (ascending) ----------------
__global__ __launch_bounds__(256) void ball_query_kernel(const float* __restrict__ xyz,
                                                         const float* __restrict__ nxyz,
                                                         int* __restrict__ ball) {
    int blk = blockIdx.x;
    int b = blk >> 10;
    int t = threadIdx.x;
    const float* Xp = xyz + (size_t)b * NPT * 3;
    float cx = nxyz[blk * 3 + 0], cy = nxyz[blk * 3 + 1], cz = nxyz[blk * 3 + 2];
    const float r2 = (float)(0.4 * 0.4);
    uint64_t mask = 0;
    int base = t * 64;
    const float4* q = (const float4*)(Xp + (size_t)base * 3);
#pragma unroll 4
    for (int c = 0; c < 16; c++) {
        float4 A = q[c * 3 + 0], B = q[c * 3 + 1], C = q[c * 3 + 2];
        float xs[4] = {A.x, A.w, B.z, C.y};
        float ys[4] = {A.y, B.x, B.w, C.z};
        float zs[4] = {A.z, B.y, C.x, C.w};
#pragma unroll
        for (int u = 0; u < 4; u++) {
            float dx = __fsub_rn(xs[u], cx);
            float dy = __fsub_rn(ys[u], cy);
            float dz = __fsub_rn(zs[u], cz);
            float d2 = __fadd_rn(__fadd_rn(__fmul_rn(dx, dx), __fmul_rn(dy, dy)), __fmul_rn(dz, dz));
            if (d2 <= r2) mask |= (1ull << (c * 4 + u));
        }
    }
    int cnt = __popcll(mask);
    int scan = cnt;
    for (int off = 1; off < 64; off <<= 1) {
        int nv = __shfl_up(scan, off);
        if ((t & 63) >= off) scan += nv;
    }
    __shared__ int s_wsum[4];
    __shared__ int s_hit[32];
    int w = t >> 6;
    if ((t & 63) == 63) s_wsum[w] = scan;
    __syncthreads();
    int woff = 0;
    for (int i = 0; i < 4; i++) if (i < w) woff += s_wsum[i];
    int excl = woff + scan - cnt;
    uint64_t mm = mask; int pos = excl;
    while (mm && pos < 32) {
        int j = __ffsll((long long)mm) - 1;
        s_hit[pos] = base + j;
        pos++;
        mm &= mm - 1;
    }
    __syncthreads();
    int total = s_wsum[0] + s_wsum[1] + s_wsum[2] + s_wsum[3];
    if (t < 32) {
        int first = s_hit[0];
        ball[blk * NK + t] = (t < total) ? s_hit[t] : first;
    }
}

// ---------------- fused group + 3xMLP + max over K ----------------
__global__ __attribute__((amdgpu_flat_work_group_size(256, 256), amdgpu_waves_per_eu(2, 2)))
void fused_mlp_kernel(const float* __restrict__ xyz,
                      const float* __restrict__ feats,
                      const float* __restrict__ ws_f,
                      const int* __restrict__ ball,
                      const float* __restrict__ nxyz,
                      float* __restrict__ out_feat) {
    int blk = blockIdx.x;
    int b = blk >> 9;
    int m0 = (blk & 511) * 2;
    int t = threadIdx.x;
    int k = t & 31, g = t >> 5;
    __shared__ float Xs[2][67][32];
    __shared__ float h1[2][64][32];
    __shared__ float h2[2][128][32];
    __shared__ int sidx[2][32];
    const float* W0t = ws_f + WS_W0T; const float* b0f = ws_f + WS_B0;
    const float* W1t = ws_f + WS_W1T; const float* b1f = ws_f + WS_B1;
    const float* W2t = ws_f + WS_W2T; const float* b2f = ws_f + WS_B2;

    if (t < 64) {
        int ctr = t >> 5;
        sidx[ctr][t & 31] = ball[((size_t)b * NM + m0 + ctr) * NK + (t & 31)];
    }
    __syncthreads();

    const float* Xp = xyz + (size_t)b * NPT * 3;
    if (g < 6) {
        int ctr = g / 3, dim = g % 3;
        float cc = nxyz[((size_t)b * NM + m0 + ctr) * 3 + dim];
        Xs[ctr][dim][k] = Xp[sidx[ctr][k] * 3 + dim] - cc;
    }
    const float* Fp = feats + (size_t)b * 64 * NPT;
#pragma unroll
    for (int i = 0; i < 8; i++) {
        int c = g + 8 * i;
        Xs[0][3 + c][k] = Fp[(size_t)c * NPT + sidx[0][k]];
        Xs[1][3 + c][k] = Fp[(size_t)c * NPT + sidx[1][k]];
    }
    __syncthreads();

    {
        float acc0[8], acc1[8];
#pragma unroll
        for (int i = 0; i < 8; i++) { acc0[i] = b0f[g * 8 + i]; acc1[i] = acc0[i]; }
#pragma unroll 4
        for (int c = 0; c < 67; c++) {
            float xv0 = Xs[0][c][k], xv1 = Xs[1][c][k];
            const float* wr = W0t + c * 64 + g * 8;
            float4 wa = *(const float4*)(wr), wb = *(const float4*)(wr + 4);
            acc0[0] = fmaf(wa.x, xv0, acc0[0]); acc1[0] = fmaf(wa.x, xv1, acc1[0]);
            acc0[1] = fmaf(wa.y, xv0, acc0[1]); acc1[1] = fmaf(wa.y, xv1, acc1[1]);
            acc0[2] = fmaf(wa.z, xv0, acc0[2]); acc1[2] = fmaf(wa.z, xv1, acc1[2]);
            acc0[3] = fmaf(wa.w, xv0, acc0[3]); acc1[3] = fmaf(wa.w, xv1, acc1[3]);
            acc0[4] = fmaf(wb.x, xv0, acc0[4]); acc1[4] = fmaf(wb.x, xv1, acc1[4]);
            acc0[5] = fmaf(wb.y, xv0, acc0[5]); acc1[5] = fmaf(wb.y, xv1, acc1[5]);
            acc0[6] = fmaf(wb.z, xv0, acc0[6]); acc1[6] = fmaf(wb.z, xv1, acc1[6]);
            acc0[7] = fmaf(wb.w, xv0, acc0[7]); acc1[7] = fmaf(wb.w, xv1, acc1[7]);
        }
#pragma unroll
        for (int i = 0; i < 8; i++) {
            h1[0][g * 8 + i][k] = fmaxf(acc0[i], 0.0f);
            h1[1][g * 8 + i][k] = fmaxf(acc1[i], 0.0f);
        }
    }
    __syncthreads();

    {
        float acc0[16], acc1[16];
#pragma unroll
        for (int i = 0; i < 16; i++) { acc0[i] = b1f[g * 16 + i]; acc1[i] = acc0[i]; }
#pragma unroll 4
        for (int c = 0; c < 64; c++) {
            float xv0 = h1[0][c][k], xv1 = h1[1][c][k];
            const float4* wr = (const float4*)(W1t + c * 128 + g * 16);
#pragma unroll
            for (int q = 0; q < 4; q++) {
                float4 wv = wr[q];
                acc0[q * 4 + 0] = fmaf(wv.x, xv0, acc0[q * 4 + 0]); acc1[q * 4 + 0] = fmaf(wv.x, xv1, acc1[q * 4 + 0]);
                acc0[q * 4 + 1] = fmaf(wv.y, xv0, acc0[q * 4 + 1]); acc1[q * 4 + 1] = fmaf(wv.y, xv1, acc1[q * 4 + 1]);
                acc0[q * 4 + 2] = fmaf(wv.z, xv0, acc0[q * 4 + 2]); acc1[q * 4 + 2] = fmaf(wv.z, xv1, acc1[q * 4 + 2]);
                acc0[q * 4 + 3] = fmaf(wv.w, xv0, acc0[q * 4 + 3]); acc1[q * 4 + 3] = fmaf(wv.w, xv1, acc1[q * 4 + 3]);
            }
        }
#pragma unroll
        for (int i = 0; i < 16; i++) {
            h2[0][g * 16 + i][k] = fmaxf(acc0[i], 0.0f);
            h2[1][g * 16 + i][k] = fmaxf(acc1[i], 0.0f);
        }
    }
    __syncthreads();

#pragma unroll
    for (int half = 0; half < 2; half++) {
        float acc0[16], acc1[16];
#pragma unroll
        for (int i = 0; i < 16; i++) { acc0[i] = b2f[g * 32 + half * 16 + i]; acc1[i] = acc0[i]; }
#pragma unroll 4
        for (int c = 0; c < 128; c++) {
            float xv0 = h2[0][c][k], xv1 = h2[1][c][k];
            const float4* wr = (const float4*)(W2t + c * 256 + g * 32 + half * 16);
#pragma unroll
            for (int q = 0; q < 4; q++) {
                float4 wv = wr[q];
                acc0[q * 4 + 0] = fmaf(wv.x, xv0, acc0[q * 4 + 0]); acc1[q * 4 + 0] = fmaf(wv.x, xv1, acc1[q * 4 + 0]);
                acc0[q * 4 + 1] = fmaf(wv.y, xv0, acc0[q * 4 + 1]); acc1[q * 4 + 1] = fmaf(wv.y, xv1, acc1[q * 4 + 1]);
                acc0[q * 4 + 2] = fmaf(wv.z, xv0, acc0[q * 4 + 2]); acc1[q * 4 + 2] = fmaf(wv.z, xv1, acc1[q * 4 + 2]);
                acc0[q * 4 + 3] = fmaf(wv.w, xv0, acc0[q * 4 + 3]); acc1[q * 4 + 3] = fmaf(wv.w, xv1, acc1[q * 4 + 3]);
            }
        }
#pragma unroll
        for (int i = 0; i < 16; i++) {
            float v0 = fmaxf(acc0[i], 0.0f);
            float v1 = fmaxf(acc1[i], 0.0f);
#pragma unroll
            for (int off = 16; off >= 1; off >>= 1) {
                v0 = fmaxf(v0, __shfl_xor(v0, off));
                v1 = fmaxf(v1, __shfl_xor(v1, off));
            }
            if (k == 0) {
                size_t o = (size_t)b * 256 + g * 32 + half * 16 + i;
                out_feat[o * NM + m0]     = v0;
                out_feat[o * NM + m0 + 1] = v1;
            }
        }
    }
}

extern "C" void kernel_launch(void* const* d_in, const int* in_sizes, int n_in,
                              void* d_out, int out_size, void* d_ws, size_t ws_size,
                              hipStream_t stream) {
    const float* xyz   = (const float*)d_in[0];
    const float* feats = (const float*)d_in[1];
    const float* W0 = (const float*)d_in[2];  const float* b0 = (const float*)d_in[3];
    const float* s0 = (const float*)d_in[4];  const float* t0 = (const float*)d_in[5];
    const float* W1 = (const float*)d_in[6];  const float* b1 = (const float*)d_in[7];
    const float* s1 = (const float*)d_in[8];  const float* t1 = (const float*)d_in[9];
    const float* W2 = (const float*)d_in[10]; const float* b2 = (const float*)d_in[11];
    const float* s2 = (const float*)d_in[12]; const float* t2 = (const float*)d_in[13];

    float* ws_f = (float*)d_ws;
    int*   idx_ws  = (int*)(ws_f + WS_IDX);
    float* nxyz_ws = ws_f + WS_NXYZ;
    int*   ball_ws = (int*)(ws_f + WS_BALL);
    float* relay_ws = ws_f + WS_RELAY;

    float* out_f = (float*)d_out;
    float* out_xyz  = out_f + OUT_XYZ;
    float* out_feat = out_f + OUT_FEAT;
    float* out_idxf = out_f + OUT_IDX;

    prep_weights<<<179, 256, 0, stream>>>(W0, b0, s0, t0, W1, b1, s1, t1, W2, b2, s2, t2, ws_f);
    if (ws_size >= (size_t)WS_END * 4) {
        relayout_kernel<<<NB, 1024, 0, stream>>>(xyz, relay_ws);
        fps3_kernel<<<NB, 1024, 0, stream>>>(xyz, relay_ws, idx_ws);
    } else {
        fps_fallback_kernel<<<NB, 1024, 0, stream>>>(xyz, idx_ws);
    }
    gather_newxyz<<<32, 256, 0, stream>>>(xyz, idx_ws, nxyz_ws, out_xyz, out_idxf);
    ball_query_kernel<<<NB * NM, 256, 0, stream>>>(xyz, nxyz_ws, ball_ws);
    fused_mlp_kernel<<<NB * NM / 2, 256, 0, stream>>>(xyz, feats, ws_f, ball_ws, nxyz_ws, out_feat);
}

// Round 11
// 2719.937 us; speedup vs baseline: 1.5718x; 1.1502x over previous
//
#include <hip/hip_runtime.h>
#include <stdint.h>

#define NB 8
#define NPT 16384
#define NM 1024
#define NK 32

// ws layout (float element offsets)
#define WS_W0T 0                    // 67*64 = 4288   W0t[c][o] = W0[o][c]*s0[o]
#define WS_B0  (WS_W0T + 4288)      // 64             b0*s0+t0
#define WS_W1T (WS_B0 + 64)         // 64*128 = 8192
#define WS_B1  (WS_W1T + 8192)      // 128
#define WS_W2T (WS_B1 + 128)        // 128*256 = 32768
#define WS_B2  (WS_W2T + 32768)     // 256
#define WS_IDX (WS_B2 + 256)        // 8192 ints (FPS indices)
#define WS_NXYZ (WS_IDX + 8192)     // 8*1024*3 = 24576 floats
#define WS_BALL (WS_NXYZ + 24576)   // 8*1024*32 = 262144 ints

// out layout (float element offsets)
#define OUT_XYZ 0
#define OUT_FEAT 24576
#define OUT_IDX (24576 + 2097152)

// ---------------- weight prep: transpose + fold BN scale ----------------
__global__ void prep_weights(const float* __restrict__ W0, const float* __restrict__ b0,
                             const float* __restrict__ s0, const float* __restrict__ t0,
                             const float* __restrict__ W1, const float* __restrict__ b1,
                             const float* __restrict__ s1, const float* __restrict__ t1,
                             const float* __restrict__ W2, const float* __restrict__ b2,
                             const float* __restrict__ s2, const float* __restrict__ t2,
                             float* __restrict__ ws) {
    int id = blockIdx.x * 256 + threadIdx.x;
    if (id < 4288) { int c = id >> 6, o = id & 63;  ws[WS_W0T + id] = W0[o * 67 + c] * s0[o]; return; }
    id -= 4288;
    if (id < 64)   { ws[WS_B0 + id] = fmaf(b0[id], s0[id], t0[id]); return; }
    id -= 64;
    if (id < 8192) { int c = id >> 7, o = id & 127; ws[WS_W1T + id] = W1[o * 64 + c] * s1[o]; return; }
    id -= 8192;
    if (id < 128)  { ws[WS_B1 + id] = fmaf(b1[id], s1[id], t1[id]); return; }
    id -= 128;
    if (id < 32768){ int c = id >> 8, o = id & 255; ws[WS_W2T + id] = W2[o * 128 + c] * s2[o]; return; }
    id -= 32768;
    if (id < 256)  { ws[WS_B2 + id] = fmaf(b2[id], s2[id], t2[id]); return; }
}

#define FOREACH32(M) M(0) M(1) M(2) M(3) M(4) M(5) M(6) M(7) \
                     M(8) M(9) M(10) M(11) M(12) M(13) M(14) M(15) \
                     M(16) M(17) M(18) M(19) M(20) M(21) M(22) M(23) \
                     M(24) M(25) M(26) M(27) M(28) M(29) M(30) M(31)

// bit-exact uniform broadcast to SGPR (R10 bug: raw readfirstlane(float) did a
// NUMERIC float->uint conversion, truncating the centroid; must bit-cast).
__device__ __forceinline__ float bcast_first(float x) {
    return __uint_as_float(__builtin_amdgcn_readfirstlane(__float_as_uint(x)));
}

// ---------------- farthest point sampling v5b: alias-blocked register residency ----------------
// ROOT CAUSE (R2-R8): with `const float* __restrict__ xyz`, LLVM REMATERIALIZES the
// loop-invariant point loads every iteration instead of keeping ~130 floats live
// (VGPR_Count 40-88 in every variant, zero scratch writes, FETCH absorbed by L2).
// Fix under test: NO __restrict on xyz/out_idx -> the in-loop out_idx store may
// alias xyz, so cross-iteration remat of the loads is illegal; values must stay
// live. waves_per_eu(2,2) @ 512 threads gives RA a 256-VGPR budget for ~130 floats.
// Centroid in SGPRs via bit-cast readfirstlane (uniform, bit-exact).
// Lean reduce: u64 pack (dist bits | ~idx, unsigned max = first-index argmax) ->
// 6-level wave butterfly -> lane0 write -> one barrier -> 3-level tail butterfly.
// Distance math: _rn intrinsics, no FMA contraction -> bit-matches reference.
__global__ __attribute__((amdgpu_flat_work_group_size(512, 512), amdgpu_waves_per_eu(2, 2)))
void fps5_kernel(const float* xyz, int* out_idx) {
    int b = blockIdx.x, t = threadIdx.x;
    const float* Xp = xyz + (size_t)b * NPT * 3;

#define DECL_PT(j) float px##j, py##j, pz##j, dd##j;
    FOREACH32(DECL_PT)
#undef DECL_PT

#define LOAD_PT(j) { int p = t + (j) * 512; \
        px##j = Xp[p * 3 + 0]; py##j = Xp[p * 3 + 1]; pz##j = Xp[p * 3 + 2]; \
        asm volatile("" : "+v"(px##j), "+v"(py##j), "+v"(pz##j)); \
        dd##j = 1e10f; }
    FOREACH32(LOAD_PT)
#undef LOAD_PT

    __shared__ uint64_t s_red[2][8];
    int farthest = 0;
    float cx = bcast_first(Xp[0]);
    float cy = bcast_first(Xp[1]);
    float cz = bcast_first(Xp[2]);
    int lane = t & 63, w = t >> 6;
    for (int it = 0; it < NM; ++it) {
        if (t == 0) out_idx[b * NM + it] = farthest;   // aliasing store: blocks remat of payload
        float best = -1.0f; int bi = 0;
        // ascending j + strict '>' => first-max wins in-thread (idx = t + j*512 ascends with j)
#define STEP_PT(j) { \
        float dx = __fsub_rn(px##j, cx); \
        float dy = __fsub_rn(py##j, cy); \
        float dz = __fsub_rn(pz##j, cz); \
        float d  = __fadd_rn(__fadd_rn(__fmul_rn(dx, dx), __fmul_rn(dy, dy)), __fmul_rn(dz, dz)); \
        dd##j = fminf(dd##j, d); \
        if (dd##j > best) { best = dd##j; bi = t + (j) * 512; } }
        FOREACH32(STEP_PT)
#undef STEP_PT
        // pack: high32 = dist bits (positive floats sort as uints), low32 = ~idx (tie -> lower idx)
        uint64_t pk = ((uint64_t)__float_as_uint(best) << 32) | (uint64_t)(uint32_t)(~(uint32_t)bi);
#pragma unroll
        for (int off = 32; off >= 1; off >>= 1) {
            uint64_t o = __shfl_xor(pk, off);
            if (o > pk) pk = o;
        }
        if (lane == 0) s_red[it & 1][w] = pk;
        __syncthreads();
        uint64_t m0 = s_red[it & 1][lane & 7];
#pragma unroll
        for (int off = 1; off < 8; off <<= 1) {
            uint64_t o = __shfl_xor(m0, off);
            if (o > m0) m0 = o;
        }
        int widx = (int)(~(uint32_t)m0);
        farthest = widx;
        const float* cp = Xp + (size_t)widx * 3;   // same addr across wave -> broadcast, L2-hit
        cx = bcast_first(cp[0]);
        cy = bcast_first(cp[1]);
        cz = bcast_first(cp[2]);
    }
}

// ---------------- gather new_xyz + emit indices as float ----------------
__global__ void gather_newxyz(const float* __restrict__ xyz, const int* __restrict__ idx_ws,
                              float* __restrict__ nxyz_ws, float* __restrict__ out_xyz,
                              float* __restrict__ out_idx_f) {
    int id = blockIdx.x * 256 + threadIdx.x;
    if (id >= NB * NM) return;
    int b = id / NM;
    int p = idx_ws[id];
    const float* Xp = xyz + ((size_t)b * NPT + p) * 3;
    float x = Xp[0], y = Xp[1], z = Xp[2];
    nxyz_ws[id * 3 + 0] = x; nxyz_ws[id * 3 + 1] = y; nxyz_ws[id * 3 + 2] = z;
    out_xyz[id * 3 + 0] = x; out_xyz[id * 3 + 1] = y; out_xyz[id * 3 + 2] = z;
    out_idx_f[id] = (float)p;
}

// ---------------- ball query: first 32 in-radius indices (ascending) ----------------
__global__ __launch_bounds__(256) void ball_query_kernel(const float* __restrict__ xyz,
                                                         const float* __restrict__ nxyz,
                                                         int* __restrict__ ball) {
    int blk = blockIdx.x;
    int b = blk >> 10;
    int t = threadIdx.x;
    const float* Xp = xyz + (size_t)b * NPT * 3;
    float cx = nxyz[blk * 3 + 0], cy = nxyz[blk * 3 + 1], cz = nxyz[blk * 3 + 2];
    const float r2 = (float)(0.4 * 0.4);
    uint64_t mask = 0;
    int base = t * 64;
    const float4* q = (const float4*)(Xp + (size_t)base * 3);
#pragma unroll 4
    for (int c = 0; c < 16; c++) {
        float4 A = q[c * 3 + 0], B = q[c * 3 + 1], C = q[c * 3 + 2];
        float xs[4] = {A.x, A.w, B.z, C.y};
        float ys[4] = {A.y, B.x, B.w, C.z};
        float zs[4] = {A.z, B.y, C.x, C.w};
#pragma unroll
        for (int u = 0; u < 4; u++) {
            float dx = __fsub_rn(xs[u], cx);
            float dy = __fsub_rn(ys[u], cy);
            float dz = __fsub_rn(zs[u], cz);
            float d2 = __fadd_rn(__fadd_rn(__fmul_rn(dx, dx), __fmul_rn(dy, dy)), __fmul_rn(dz, dz));
            if (d2 <= r2) mask |= (1ull << (c * 4 + u));
        }
    }
    int cnt = __popcll(mask);
    int scan = cnt;
    for (int off = 1; off < 64; off <<= 1) {
        int nv = __shfl_up(scan, off);
        if ((t & 63) >= off) scan += nv;
    }
    __shared__ int s_wsum[4];
    __shared__ int s_hit[32];
    int w = t >> 6;
    if ((t & 63) == 63) s_wsum[w] = scan;
    __syncthreads();
    int woff = 0;
    for (int i = 0; i < 4; i++) if (i < w) woff += s_wsum[i];
    int excl = woff + scan - cnt;
    uint64_t mm = mask; int pos = excl;
    while (mm && pos < 32) {
        int j = __ffsll((long long)mm) - 1;
        s_hit[pos] = base + j;
        pos++;
        mm &= mm - 1;
    }
    __syncthreads();
    int total = s_wsum[0] + s_wsum[1] + s_wsum[2] + s_wsum[3];
    if (t < 32) {
        int first = s_hit[0];
        ball[blk * NK + t] = (t < total) ? s_hit[t] : first;
    }
}

// ---------------- fused group + 3xMLP + max over K ----------------
__global__ __attribute__((amdgpu_flat_work_group_size(256, 256), amdgpu_waves_per_eu(2, 2)))
void fused_mlp_kernel(const float* __restrict__ xyz,
                      const float* __restrict__ feats,
                      const float* __restrict__ ws_f,
                      const int* __restrict__ ball,
                      const float* __restrict__ nxyz,
                      float* __restrict__ out_feat) {
    int blk = blockIdx.x;
    int b = blk >> 9;
    int m0 = (blk & 511) * 2;
    int t = threadIdx.x;
    int k = t & 31, g = t >> 5;
    __shared__ float Xs[2][67][32];
    __shared__ float h1[2][64][32];
    __shared__ float h2[2][128][32];
    __shared__ int sidx[2][32];
    const float* W0t = ws_f + WS_W0T; const float* b0f = ws_f + WS_B0;
    const float* W1t = ws_f + WS_W1T; const float* b1f = ws_f + WS_B1;
    const float* W2t = ws_f + WS_W2T; const float* b2f = ws_f + WS_B2;

    if (t < 64) {
        int ctr = t >> 5;
        sidx[ctr][t & 31] = ball[((size_t)b * NM + m0 + ctr) * NK + (t & 31)];
    }
    __syncthreads();

    const float* Xp = xyz + (size_t)b * NPT * 3;
    if (g < 6) {
        int ctr = g / 3, dim = g % 3;
        float cc = nxyz[((size_t)b * NM + m0 + ctr) * 3 + dim];
        Xs[ctr][dim][k] = Xp[sidx[ctr][k] * 3 + dim] - cc;
    }
    const float* Fp = feats + (size_t)b * 64 * NPT;
#pragma unroll
    for (int i = 0; i < 8; i++) {
        int c = g + 8 * i;
        Xs[0][3 + c][k] = Fp[(size_t)c * NPT + sidx[0][k]];
        Xs[1][3 + c][k] = Fp[(size_t)c * NPT + sidx[1][k]];
    }
    __syncthreads();

    {
        float acc0[8], acc1[8];
#pragma unroll
        for (int i = 0; i < 8; i++) { acc0[i] = b0f[g * 8 + i]; acc1[i] = acc0[i]; }
#pragma unroll 4
        for (int c = 0; c < 67; c++) {
            float xv0 = Xs[0][c][k], xv1 = Xs[1][c][k];
            const float* wr = W0t + c * 64 + g * 8;
            float4 wa = *(const float4*)(wr), wb = *(const float4*)(wr + 4);
            acc0[0] = fmaf(wa.x, xv0, acc0[0]); acc1[0] = fmaf(wa.x, xv1, acc1[0]);
            acc0[1] = fmaf(wa.y, xv0, acc0[1]); acc1[1] = fmaf(wa.y, xv1, acc1[1]);
            acc0[2] = fmaf(wa.z, xv0, acc0[2]); acc1[2] = fmaf(wa.z, xv1, acc1[2]);
            acc0[3] = fmaf(wa.w, xv0, acc0[3]); acc1[3] = fmaf(wa.w, xv1, acc1[3]);
            acc0[4] = fmaf(wb.x, xv0, acc0[4]); acc1[4] = fmaf(wb.x, xv1, acc1[4]);
            acc0[5] = fmaf(wb.y, xv0, acc0[5]); acc1[5] = fmaf(wb.y, xv1, acc1[5]);
            acc0[6] = fmaf(wb.z, xv0, acc0[6]); acc1[6] = fmaf(wb.z, xv1, acc1[6]);
            acc0[7] = fmaf(wb.w, xv0, acc0[7]); acc1[7] = fmaf(wb.w, xv1, acc1[7]);
        }
#pragma unroll
        for (int i = 0; i < 8; i++) {
            h1[0][g * 8 + i][k] = fmaxf(acc0[i], 0.0f);
            h1[1][g * 8 + i][k] = fmaxf(acc1[i], 0.0f);
        }
    }
    __syncthreads();

    {
        float acc0[16], acc1[16];
#pragma unroll
        for (int i = 0; i < 16; i++) { acc0[i] = b1f[g * 16 + i]; acc1[i] = acc0[i]; }
#pragma unroll 4
        for (int c = 0; c < 64; c++) {
            float xv0 = h1[0][c][k], xv1 = h1[1][c][k];
            const float4* wr = (const float4*)(W1t + c * 128 + g * 16);
#pragma unroll
            for (int q = 0; q < 4; q++) {
                float4 wv = wr[q];
                acc0[q * 4 + 0] = fmaf(wv.x, xv0, acc0[q * 4 + 0]); acc1[q * 4 + 0] = fmaf(wv.x, xv1, acc1[q * 4 + 0]);
                acc0[q * 4 + 1] = fmaf(wv.y, xv0, acc0[q * 4 + 1]); acc1[q * 4 + 1] = fmaf(wv.y, xv1, acc1[q * 4 + 1]);
                acc0[q * 4 + 2] = fmaf(wv.z, xv0, acc0[q * 4 + 2]); acc1[q * 4 + 2] = fmaf(wv.z, xv1, acc1[q * 4 + 2]);
                acc0[q * 4 + 3] = fmaf(wv.w, xv0, acc0[q * 4 + 3]); acc1[q * 4 + 3] = fmaf(wv.w, xv1, acc1[q * 4 + 3]);
            }
        }
#pragma unroll
        for (int i = 0; i < 16; i++) {
            h2[0][g * 16 + i][k] = fmaxf(acc0[i], 0.0f);
            h2[1][g * 16 + i][k] = fmaxf(acc1[i], 0.0f);
        }
    }
    __syncthreads();

#pragma unroll
    for (int half = 0; half < 2; half++) {
        float acc0[16], acc1[16];
#pragma unroll
        for (int i = 0; i < 16; i++) { acc0[i] = b2f[g * 32 + half * 16 + i]; acc1[i] = acc0[i]; }
#pragma unroll 4
        for (int c = 0; c < 128; c++) {
            float xv0 = h2[0][c][k], xv1 = h2[1][c][k];
            const float4* wr = (const float4*)(W2t + c * 256 + g * 32 + half * 16);
#pragma unroll
            for (int q = 0; q < 4; q++) {
                float4 wv = wr[q];
                acc0[q * 4 + 0] = fmaf(wv.x, xv0, acc0[q * 4 + 0]); acc1[q * 4 + 0] = fmaf(wv.x, xv1, acc1[q * 4 + 0]);
                acc0[q * 4 + 1] = fmaf(wv.y, xv0, acc0[q * 4 + 1]); acc1[q * 4 + 1] = fmaf(wv.y, xv1, acc1[q * 4 + 1]);
                acc0[q * 4 + 2] = fmaf(wv.z, xv0, acc0[q * 4 + 2]); acc1[q * 4 + 2] = fmaf(wv.z, xv1, acc1[q * 4 + 2]);
                acc0[q * 4 + 3] = fmaf(wv.w, xv0, acc0[q * 4 + 3]); acc1[q * 4 + 3] = fmaf(wv.w, xv1, acc1[q * 4 + 3]);
            }
        }
#pragma unroll
        for (int i = 0; i < 16; i++) {
            float v0 = fmaxf(acc0[i], 0.0f);
            float v1 = fmaxf(acc1[i], 0.0f);
#pragma unroll
            for (int off = 16; off >= 1; off >>= 1) {
                v0 = fmaxf(v0, __shfl_xor(v0, off));
                v1 = fmaxf(v1, __shfl_xor(v1, off));
            }
            if (k == 0) {
                size_t o = (size_t)b * 256 + g * 32 + half * 16 + i;
                out_feat[o * NM + m0]     = v0;
                out_feat[o * NM + m0 + 1] = v1;
            }
        }
    }
}

extern "C" void kernel_launch(void* const* d_in, const int* in_sizes, int n_in,
                              void* d_out, int out_size, void* d_ws, size_t ws_size,
                              hipStream_t stream) {
    const float* xyz   = (const float*)d_in[0];
    const float* feats = (const float*)d_in[1];
    const float* W0 = (const float*)d_in[2];  const float* b0 = (const float*)d_in[3];
    const float* s0 = (const float*)d_in[4];  const float* t0 = (const float*)d_in[5];
    const float* W1 = (const float*)d_in[6];  const float* b1 = (const float*)d_in[7];
    const float* s1 = (const float*)d_in[8];  const float* t1 = (const float*)d_in[9];
    const float* W2 = (const float*)d_in[10]; const float* b2 = (const float*)d_in[11];
    const float* s2 = (const float*)d_in[12]; const float* t2 = (const float*)d_in[13];

    float* ws_f = (float*)d_ws;
    int*   idx_ws  = (int*)(ws_f + WS_IDX);
    float* nxyz_ws = ws_f + WS_NXYZ;
    int*   ball_ws = (int*)(ws_f + WS_BALL);

    float* out_f = (float*)d_out;
    float* out_xyz  = out_f + OUT_XYZ;
    float* out_feat = out_f + OUT_FEAT;
    float* out_idxf = out_f + OUT_IDX;

    prep_weights<<<179, 256, 0, stream>>>(W0, b0, s0, t0, W1, b1, s1, t1, W2, b2, s2, t2, ws_f);
    fps5_kernel<<<NB, 512, 0, stream>>>((float*)xyz, idx_ws);
    gather_newxyz<<<32, 256, 0, stream>>>(xyz, idx_ws, nxyz_ws, out_xyz, out_idxf);
    ball_query_kernel<<<NB * NM, 256, 0, stream>>>(xyz, nxyz_ws, ball_ws);
    fused_mlp_kernel<<<NB * NM / 2, 256, 0, stream>>>(xyz, feats, ws_f, ball_ws, nxyz_ws, out_feat);
}